// Round 5
// baseline (155.830 us; speedup 1.0000x reference)
//
#include <hip/hip_runtime.h>

// Batched Thomas solve, B=2048 rows, N=8192, fp32 — SCAN-FREE version.
//
// R9 vs R8 (post-mortem: R8 finally spill-free, WRITE=65536KB exact, but dur
// stuck at 55us = VALU-issue + scan-structure wall: 3 shuffle scans, 64 LDS
// array ops, 3 barriers, 3x coeff recompute).
// Key domain fact: alpha in [0,0.3) => a=al^2<=0.09, b>=1, c=al^2+2al<0.69.
// Forward sensitivity dcp_k/dcp_{k-1} = c*a/den^2 <= 0.072, ddp<=0.096;
// backward decay |cp|<=0.738. Influence is LOCAL:
//   - 8-elem forward warm-up: error <= 0.072^8 ~ 8e-10
//   - 32-elem backward tail:  worst-case 0.738^32*|u|max ~ 1.1e-3 << 0.015625
//     (realistic alphas: ~1e-15); row edges are exact boundaries.
// => Each thread computes its 32 outputs INDEPENDENTLY: forward sweep over
// [base-8, base+64), accumulating u_in = sum(prod*dp) during the tail with
// O(1) state, then register back-substitution. No barriers, no shuffles,
// no LDS, no inter-thread communication. ~24 VALU/elem vs R8's ~62.
// launch_bounds(256,4) => 128 regs; live set ~92 (cpv+dpv 64 + window).

#define NN 8192
#define TB 256
#define CH 32          // NN / TB outputs per thread
#define MF 8           // forward warm-up elements
#define MB 32          // backward tail elements

__device__ __forceinline__ float frcp(float x) { return __builtin_amdgcn_rcpf(x); }

// One forward Thomas step at position j.
//   carries: cp, dp, sqm (= alpha_{j-1}^2), a0 (= alpha_j), sq0 (= alpha_j^2)
//   inputs:  AP1 = alpha_{j+1}, FJ = f_j
#define FSTEP_CORE(AP1, FJ)                                \
    const float ap1 = (AP1);                               \
    const float sqp = ap1 * ap1;                           \
    const float c   = __builtin_fmaf(ap1, 2.0f, sqp);      \
    const float b   = __builtin_fmaf(sq0, a0, 1.0f);       \
    const float den = __builtin_fmaf(-sqm, cp, b);         \
    const float rd  = frcp(den);                           \
    cp = c * rd;                                           \
    dp = __builtin_fmaf(-sqm, dp, (FJ)) * rd;              \
    sqm = sq0; a0 = ap1; sq0 = sqp;

#define WSTEP(AP1, FJ) { FSTEP_CORE(AP1, FJ) }

__global__ __launch_bounds__(TB, 4)
void thomas_trunc_kernel(const float* __restrict__ alpha,
                         const float* __restrict__ fvec,
                         float* __restrict__ out)
{
    const int t   = threadIdx.x;
    const int row = blockIdx.x;
    const float* __restrict__ arow = alpha + (size_t)row * NN;
    const int base = t * CH;

    // forward rolling state
    float cp = 0.f, dp = 0.f;
    float a0, sq0, sqm;

    const float aB = arow[base];

    // ---- warm-up over [base-MF, base): converges cp,dp to ~1e-9 ----
    if (t > 0) {
        const float am9 = arow[base - MF - 1];
        const float4* w4 = reinterpret_cast<const float4*>(arow + base - MF);
        const float4* g4 = reinterpret_cast<const float4*>(fvec + base - MF);
        const float4 W0 = w4[0], W1 = w4[1];
        const float4 G0 = g4[0], G1 = g4[1];
        sqm = am9 * am9;
        a0  = W0.x; sq0 = a0 * a0;
        WSTEP(W0.y, G0.x) WSTEP(W0.z, G0.y) WSTEP(W0.w, G0.z) WSTEP(W1.x, G0.w)
        WSTEP(W1.y, G1.x) WSTEP(W1.z, G1.y) WSTEP(W1.w, G1.z) WSTEP(aB,   G1.w)
    } else {
        sqm = 0.f;          // a_0 = 0 (true boundary)
        a0  = aB; sq0 = aB * aB;
    }

    // ---- chunk: 32 exact-algorithm steps, cp/dp kept in registers ----
    float cpv[CH], dpv[CH];
    const float peek = (t < TB - 1) ? arow[base + CH] : 0.f;  // c_{N-1} = 0
    {
        const float4* a4 = reinterpret_cast<const float4*>(arow + base);
        const float4* f4 = reinterpret_cast<const float4*>(fvec + base);
        float4 aq = a4[0];
        #pragma unroll
        for (int g = 0; g < CH / 4; ++g) {
            const float4 fq  = f4[g];
            const float4 aqn = (g < CH / 4 - 1) ? a4[g + 1]
                                                : make_float4(peek, 0.f, 0.f, 0.f);
            { FSTEP_CORE(aq.y,  fq.x) cpv[4*g+0] = cp; dpv[4*g+0] = dp; }
            { FSTEP_CORE(aq.z,  fq.y) cpv[4*g+1] = cp; dpv[4*g+1] = dp; }
            { FSTEP_CORE(aq.w,  fq.z) cpv[4*g+2] = cp; dpv[4*g+2] = dp; }
            { FSTEP_CORE(aqn.x, fq.w) cpv[4*g+3] = cp; dpv[4*g+3] = dp; }
            aq = aqn;
        }
    }

    // ---- tail: 32 more forward steps, accumulating u_in on the fly ----
    // u_{base+CH} = sum_j (prod_{l<j} -cp_l) * dp_j   (truncated after MB)
    float u = 0.f;
    if (t < TB - 1) {
        const float peek2 = (t < TB - 2) ? arow[base + CH + MB] : 0.f;
        const float4* a4 = reinterpret_cast<const float4*>(arow + base + CH);
        const float4* f4 = reinterpret_cast<const float4*>(fvec + base + CH);
        float prod = 1.f, uacc = 0.f;
        float4 aq = a4[0];   // aq.x == alpha[base+CH] == current a0 carry
        #pragma unroll
        for (int g = 0; g < MB / 4; ++g) {
            const float4 fq  = f4[g];
            const float4 aqn = (g < MB / 4 - 1) ? a4[g + 1]
                                                : make_float4(peek2, 0.f, 0.f, 0.f);
            { FSTEP_CORE(aq.y,  fq.x) uacc = __builtin_fmaf(prod, dp, uacc); prod = prod * (-cp); }
            { FSTEP_CORE(aq.z,  fq.y) uacc = __builtin_fmaf(prod, dp, uacc); prod = prod * (-cp); }
            { FSTEP_CORE(aq.w,  fq.z) uacc = __builtin_fmaf(prod, dp, uacc); prod = prod * (-cp); }
            { FSTEP_CORE(aqn.x, fq.w) uacc = __builtin_fmaf(prod, dp, uacc); prod = prod * (-cp); }
            aq = aqn;
        }
        u = uacc;
    }
    // t == TB-1: u_in = 0 exactly (true boundary u_N = 0)

    // ---- back-substitution from registers + float4 stores ----
    float4* o4 = reinterpret_cast<float4*>(out + (size_t)row * NN + base);
    #pragma unroll
    for (int g = CH / 4 - 1; g >= 0; --g) {
        const float u3 = __builtin_fmaf(-cpv[4*g+3], u,  dpv[4*g+3]);
        const float u2 = __builtin_fmaf(-cpv[4*g+2], u3, dpv[4*g+2]);
        const float u1 = __builtin_fmaf(-cpv[4*g+1], u2, dpv[4*g+1]);
        const float u0 = __builtin_fmaf(-cpv[4*g+0], u1, dpv[4*g+0]);
        o4[g] = make_float4(u0, u1, u2, u3);
        u = u0;
    }
}

extern "C" void kernel_launch(void* const* d_in, const int* in_sizes, int n_in,
                              void* d_out, int out_size, void* d_ws, size_t ws_size,
                              hipStream_t stream) {
    const float* alpha = (const float*)d_in[0];
    const float* fvec  = (const float*)d_in[1];
    float* out = (float*)d_out;
    const int nrows = out_size / NN;   // 2048
    thomas_trunc_kernel<<<nrows, TB, 0, stream>>>(alpha, fvec, out);
}

// Round 6
// 148.491 us; speedup vs baseline: 1.0494x; 1.0494x over previous
//
#include <hip/hip_runtime.h>

// Batched Thomas solve, B=2048 rows, N=8192, fp32 — SCAN-FREE version.
//
// R10 vs R9 (post-mortem: algorithm fine, VALU-busy time only ~9.5us, but
// the backend spilled cpv/dpv: VGPR_Count=64 despite launch_bounds(256,4)
// allowing 128 -- the allocator's occupancy heuristic targeted 8 waves/EU
// and spilled ~48MB to scratch (WRITE 113MB, FETCH 56MB, VALUBusy 13%,
// occupancy 33%). Same "insists on 64 regs" behavior as R2-R8.)
// Fix: ONE change -- force the 4-waves/EU operating point with
// __attribute__((amdgpu_waves_per_eu(2,4))): min=2 raises the budget to
// 256 regs, max=4 removes any incentive to stay at the 64-reg point.
// Live set ~100 regs (cpv+dpv 64 + rolling state + float4 staging) fits 128.
//
// Numerics (unchanged from R9): alpha in [0,0.3) => forward influence decays
// x14/elem (8-elem warm-up, err ~8e-10); backward |cp|<=0.738 (32-elem tail,
// worst-case 6e-5 * |u|max ~ 1.4e-3 << tol; realistic ~1e-13). Row edges
// exact. Each thread computes 32 outputs independently: forward over
// [base-8, base+64), u_in accumulated on the fly in the tail (O(1) state),
// then register back-substitution. No barriers/shuffles/LDS.

#define NN 8192
#define TB 256
#define CH 32          // NN / TB outputs per thread
#define MF 8           // forward warm-up elements
#define MB 32          // backward tail elements

__device__ __forceinline__ float frcp(float x) { return __builtin_amdgcn_rcpf(x); }

// One forward Thomas step at position j.
//   carries: cp, dp, sqm (= alpha_{j-1}^2), a0 (= alpha_j), sq0 (= alpha_j^2)
//   inputs:  AP1 = alpha_{j+1}, FJ = f_j
#define FSTEP_CORE(AP1, FJ)                                \
    const float ap1 = (AP1);                               \
    const float sqp = ap1 * ap1;                           \
    const float c   = __builtin_fmaf(ap1, 2.0f, sqp);      \
    const float b   = __builtin_fmaf(sq0, a0, 1.0f);       \
    const float den = __builtin_fmaf(-sqm, cp, b);         \
    const float rd  = frcp(den);                           \
    cp = c * rd;                                           \
    dp = __builtin_fmaf(-sqm, dp, (FJ)) * rd;              \
    sqm = sq0; a0 = ap1; sq0 = sqp;

#define WSTEP(AP1, FJ) { FSTEP_CORE(AP1, FJ) }

__global__ __launch_bounds__(TB)
__attribute__((amdgpu_waves_per_eu(2, 4)))
void thomas_trunc_kernel(const float* __restrict__ alpha,
                         const float* __restrict__ fvec,
                         float* __restrict__ out)
{
    const int t   = threadIdx.x;
    const int row = blockIdx.x;
    const float* __restrict__ arow = alpha + (size_t)row * NN;
    const int base = t * CH;

    // forward rolling state
    float cp = 0.f, dp = 0.f;
    float a0, sq0, sqm;

    const float aB = arow[base];

    // ---- warm-up over [base-MF, base): converges cp,dp to ~1e-9 ----
    if (t > 0) {
        const float am9 = arow[base - MF - 1];
        const float4* w4 = reinterpret_cast<const float4*>(arow + base - MF);
        const float4* g4 = reinterpret_cast<const float4*>(fvec + base - MF);
        const float4 W0 = w4[0], W1 = w4[1];
        const float4 G0 = g4[0], G1 = g4[1];
        sqm = am9 * am9;
        a0  = W0.x; sq0 = a0 * a0;
        WSTEP(W0.y, G0.x) WSTEP(W0.z, G0.y) WSTEP(W0.w, G0.z) WSTEP(W1.x, G0.w)
        WSTEP(W1.y, G1.x) WSTEP(W1.z, G1.y) WSTEP(W1.w, G1.z) WSTEP(aB,   G1.w)
    } else {
        sqm = 0.f;          // a_0 = 0 (true boundary)
        a0  = aB; sq0 = aB * aB;
    }

    // ---- chunk: 32 exact-algorithm steps, cp/dp kept in registers ----
    float cpv[CH], dpv[CH];
    const float peek = (t < TB - 1) ? arow[base + CH] : 0.f;  // c_{N-1} = 0
    {
        const float4* a4 = reinterpret_cast<const float4*>(arow + base);
        const float4* f4 = reinterpret_cast<const float4*>(fvec + base);
        float4 aq = a4[0];
        #pragma unroll
        for (int g = 0; g < CH / 4; ++g) {
            const float4 fq  = f4[g];
            const float4 aqn = (g < CH / 4 - 1) ? a4[g + 1]
                                                : make_float4(peek, 0.f, 0.f, 0.f);
            { FSTEP_CORE(aq.y,  fq.x) cpv[4*g+0] = cp; dpv[4*g+0] = dp; }
            { FSTEP_CORE(aq.z,  fq.y) cpv[4*g+1] = cp; dpv[4*g+1] = dp; }
            { FSTEP_CORE(aq.w,  fq.z) cpv[4*g+2] = cp; dpv[4*g+2] = dp; }
            { FSTEP_CORE(aqn.x, fq.w) cpv[4*g+3] = cp; dpv[4*g+3] = dp; }
            aq = aqn;
        }
    }

    // ---- tail: 32 more forward steps, accumulating u_in on the fly ----
    // u_{base+CH} = sum_j (prod_{l<j} -cp_l) * dp_j   (truncated after MB)
    float u = 0.f;
    if (t < TB - 1) {
        const float peek2 = (t < TB - 2) ? arow[base + CH + MB] : 0.f;
        const float4* a4 = reinterpret_cast<const float4*>(arow + base + CH);
        const float4* f4 = reinterpret_cast<const float4*>(fvec + base + CH);
        float prod = 1.f, uacc = 0.f;
        float4 aq = a4[0];   // aq.x == alpha[base+CH] == current a0 carry
        #pragma unroll
        for (int g = 0; g < MB / 4; ++g) {
            const float4 fq  = f4[g];
            const float4 aqn = (g < MB / 4 - 1) ? a4[g + 1]
                                                : make_float4(peek2, 0.f, 0.f, 0.f);
            { FSTEP_CORE(aq.y,  fq.x) uacc = __builtin_fmaf(prod, dp, uacc); prod = prod * (-cp); }
            { FSTEP_CORE(aq.z,  fq.y) uacc = __builtin_fmaf(prod, dp, uacc); prod = prod * (-cp); }
            { FSTEP_CORE(aq.w,  fq.z) uacc = __builtin_fmaf(prod, dp, uacc); prod = prod * (-cp); }
            { FSTEP_CORE(aqn.x, fq.w) uacc = __builtin_fmaf(prod, dp, uacc); prod = prod * (-cp); }
            aq = aqn;
        }
        u = uacc;
    }
    // t == TB-1: u_in = 0 exactly (true boundary u_N = 0)

    // ---- back-substitution from registers + float4 stores ----
    float4* o4 = reinterpret_cast<float4*>(out + (size_t)row * NN + base);
    #pragma unroll
    for (int g = CH / 4 - 1; g >= 0; --g) {
        const float u3 = __builtin_fmaf(-cpv[4*g+3], u,  dpv[4*g+3]);
        const float u2 = __builtin_fmaf(-cpv[4*g+2], u3, dpv[4*g+2]);
        const float u1 = __builtin_fmaf(-cpv[4*g+1], u2, dpv[4*g+1]);
        const float u0 = __builtin_fmaf(-cpv[4*g+0], u1, dpv[4*g+0]);
        o4[g] = make_float4(u0, u1, u2, u3);
        u = u0;
    }
}

extern "C" void kernel_launch(void* const* d_in, const int* in_sizes, int n_in,
                              void* d_out, int out_size, void* d_ws, size_t ws_size,
                              hipStream_t stream) {
    const float* alpha = (const float*)d_in[0];
    const float* fvec  = (const float*)d_in[1];
    float* out = (float*)d_out;
    const int nrows = out_size / NN;   // 2048
    thomas_trunc_kernel<<<nrows, TB, 0, stream>>>(alpha, fvec, out);
}